// Round 19
// baseline (218.715 us; speedup 1.0000x reference)
//
#include <hip/hip_runtime.h>
#include <hip/hip_bf16.h>
#include <cstdint>

// out[M,N] = x[M,K] @ weight[N,K]^T, fp32 device buffers.
// TWO plain dispatches, pure-arithmetic path selection (R14 lesson).
//   1) reset_cnt<<<1,1>>>
//   2) persist_cvt_gemm<<<256,512>>> (1 block/CU):
//      phase 1: coalesced LDS-staged cvt fp32->bf16 into d_ws (R14 exact)
//      agent-scope atomic grid barrier
//      phase 2: 256x256 GEMM, 8 waves, 16x16x32 MFMA. R19: DEPTH-2 pipeline:
//        BK=32 sub-steps, LDS triple-buffered (3 x (A16+B16) KB = 96 KB),
//        stage tile t+2 while computing t -> prefetch distance ~2 K-steps
//        (~5000 cyc >> load latency); vmcnt(8) retires exactly set t.
//        Per step: 4 gload_lds/wave, 12 ds_read_b128, 32 MFMA, 2 barriers.

typedef __bf16 bf16x8 __attribute__((ext_vector_type(8)));
typedef float f32x4 __attribute__((ext_vector_type(4)));
typedef unsigned short u16x8 __attribute__((ext_vector_type(8)));

#define GAS __attribute__((address_space(1)))
#define LAS __attribute__((address_space(3)))
#define ASYNC16(gsrc, ldst)                                                  \
    __builtin_amdgcn_global_load_lds((GAS uint32_t*)(const void*)(gsrc),     \
                                     (LAS uint32_t*)(ldst), 16, 0, 0)

__device__ inline unsigned short f2bf(float f) {
    __hip_bfloat16 h = __float2bfloat16(f);  // RNE
    return *reinterpret_cast<unsigned short*>(&h);
}

__global__ void reset_cnt(unsigned int* cnt) {
    atomicExch(cnt, 0u);
}

__global__ __launch_bounds__(512, 1) void persist_cvt_gemm(
    const float* __restrict__ A32,       // x      [M,K]
    const float* __restrict__ B32,       // weight [N,K]
    unsigned short* __restrict__ ws,     // bf16 tiled [szX | szW]
    unsigned int* __restrict__ cnt,      // grid-barrier counter
    float* __restrict__ C,               // out    [M,N]
    int M, int N, int K)
{
    const int NT  = K >> 6;              // 64 (chunks of 16384 shorts)
    const int szX = M * K;
    const int szW = N * K;

    __shared__ unsigned short lds3[3][2][8192];  // 96 KB: 3 sets x (A 16K + B 16K)

    const int tid = threadIdx.x;

    // ================= phase 1: coalesced LDS-staged cvt (R14 exact) ==========
    // chunk = one (tile256, kt64): [koct 8][row 256][8] bf16 = 32 KB;
    // off = koct*2048 + row*8, k_local = koct*8.
    {
        const int CH_A = (M >> 8) * NT;
        const int CH_T = CH_A + (N >> 8) * NT;
        unsigned short* cbuf = &lds3[0][0][0];   // 32 KB contiguous scratch
        for (int cid = blockIdx.x; cid < CH_T; cid += gridDim.x) {
            int cl; const float* base; unsigned short* dstc;
            if (cid < CH_A) { cl = cid;        base = A32; dstc = ws + ((size_t)cl << 14); }
            else            { cl = cid - CH_A; base = B32; dstc = ws + (size_t)szX + ((size_t)cl << 14); }
            const int tile = cl >> 6, kt = cl & 63;
            const float* srcc = base + ((size_t)(tile << 8)) * K + (kt << 6);
#pragma unroll
            for (int p = 0; p < 4; ++p) {
                const int row = (p << 6) + (tid >> 3);
                const int kg  = tid & 7;
                const float* s = srcc + (size_t)row * K + (kg << 3);
                float4 v0 = *reinterpret_cast<const float4*>(s);
                float4 v1 = *reinterpret_cast<const float4*>(s + 4);
                u16x8 o;
                o[0] = f2bf(v0.x); o[1] = f2bf(v0.y); o[2] = f2bf(v0.z); o[3] = f2bf(v0.w);
                o[4] = f2bf(v1.x); o[5] = f2bf(v1.y); o[6] = f2bf(v1.z); o[7] = f2bf(v1.w);
                *reinterpret_cast<u16x8*>(&cbuf[kg * 2048 + row * 8]) = o;
            }
            __syncthreads();
#pragma unroll
            for (int p = 0; p < 4; ++p) {
                const int off = (p << 12) + (tid << 3);
                *reinterpret_cast<u16x8*>(dstc + off) =
                    *reinterpret_cast<const u16x8*>(&cbuf[off]);
            }
            __syncthreads();
        }
    }

    // ============ grid barrier (agent scope) ============
    {
        __syncthreads();
        if (tid == 0) {
            __threadfence();
            __hip_atomic_fetch_add(cnt, 1u, __ATOMIC_ACQ_REL, __HIP_MEMORY_SCOPE_AGENT);
            while (__hip_atomic_load(cnt, __ATOMIC_ACQUIRE, __HIP_MEMORY_SCOPE_AGENT)
                   < gridDim.x) {
                __builtin_amdgcn_s_sleep(2);
            }
        }
        __syncthreads();
    }
    asm volatile("s_waitcnt vmcnt(0)" ::: "memory");   // clean vmcnt ledger

    // ================= phase 2: GEMM (depth-2, BK=32, 3 LDS sets) ==========
    const int nbm = M >> 8;              // 8
    const int nbn = N >> 8;              // 32
    const int bid = blockIdx.x;
    const int swzid = (bid & 7) * ((nbm * nbn) >> 3) + (bid >> 3);
    const int bm = swzid % nbm;          // fast: stream A panels
    const int bn = swzid / nbm;          // slow: B panel L2-resident

    const int wv   = tid >> 6;
    const int lane = tid & 63;
    const int wr   = wv >> 2;            // 0..1
    const int wc   = wv & 3;             // 0..3

    // BK=32 sub-step s reads ws at panel + s*8192 (chunk halves contiguous)
    const unsigned short* wsA = ws + (size_t)(bm * NT) * 16384 + wv * 1024 + lane * 8;
    const unsigned short* wsB = ws + (size_t)szX + (size_t)(bn * NT) * 16384 + wv * 1024 + lane * 8;

    // fragment bases within a 16KB half: [koct' 4][row 256][8]
    const int aBase = (lane >> 4) * 2048 + (wr * 128 + (lane & 15)) * 8;
    const int bBase = (lane >> 4) * 2048 + (wc * 64 + (lane & 15)) * 8;

    f32x4 acc[8][4] = {};

#define STAGE32(t32, ss) do {                                                 \
        const unsigned short* sA_ = wsA + (size_t)(t32) * 8192;               \
        const unsigned short* sB_ = wsB + (size_t)(t32) * 8192;               \
        ASYNC16(sA_,       &lds3[ss][0][wv * 1024]);                          \
        ASYNC16(sA_ + 512, &lds3[ss][0][wv * 1024 + 512]);                    \
        ASYNC16(sB_,       &lds3[ss][1][wv * 1024]);                          \
        ASYNC16(sB_ + 512, &lds3[ss][1][wv * 1024 + 512]);                    \
    } while (0)
#define DSA3(ss, fm) (*(const bf16x8*)&lds3[ss][0][aBase + (fm) * 128])
#define DSB3(ss, fn) (*(const bf16x8*)&lds3[ss][1][bBase + (fn) * 128])

    const int NT32 = K >> 5;             // 128 sub-steps

    // prologue: sets 0,1 <- tiles 0,1 (8 outstanding = steady state)
    STAGE32(0, 0);
    STAGE32(1, 1);

    for (int t = 0; t < NT32; ++t) {
        const int ss = t % 3;
        const int sn = (t + 2) % 3;
        const int tn = (t + 2 < NT32) ? t + 2 : NT32 - 1;  // tail: redundant
        STAGE32(tn, sn);
        // ledger: sets t(4),t+1(4),t+2(4) <= 12 outstanding; vmcnt(8)
        // retires exactly set t (oldest 4). Never 0 in loop.
        asm volatile("s_waitcnt vmcnt(8)" ::: "memory");
        __builtin_amdgcn_s_barrier();
        __builtin_amdgcn_sched_barrier(0);

        bf16x8 a0 = DSA3(ss,0), a1 = DSA3(ss,1), a2 = DSA3(ss,2), a3 = DSA3(ss,3);
        bf16x8 a4 = DSA3(ss,4), a5 = DSA3(ss,5), a6 = DSA3(ss,6), a7 = DSA3(ss,7);
        bf16x8 b0 = DSB3(ss,0), b1 = DSB3(ss,1), b2 = DSB3(ss,2), b3 = DSB3(ss,3);
        __builtin_amdgcn_s_setprio(1);
        acc[0][0] = __builtin_amdgcn_mfma_f32_16x16x32_bf16(a0, b0, acc[0][0], 0, 0, 0);
        acc[0][1] = __builtin_amdgcn_mfma_f32_16x16x32_bf16(a0, b1, acc[0][1], 0, 0, 0);
        acc[0][2] = __builtin_amdgcn_mfma_f32_16x16x32_bf16(a0, b2, acc[0][2], 0, 0, 0);
        acc[0][3] = __builtin_amdgcn_mfma_f32_16x16x32_bf16(a0, b3, acc[0][3], 0, 0, 0);
        acc[1][0] = __builtin_amdgcn_mfma_f32_16x16x32_bf16(a1, b0, acc[1][0], 0, 0, 0);
        acc[1][1] = __builtin_amdgcn_mfma_f32_16x16x32_bf16(a1, b1, acc[1][1], 0, 0, 0);
        acc[1][2] = __builtin_amdgcn_mfma_f32_16x16x32_bf16(a1, b2, acc[1][2], 0, 0, 0);
        acc[1][3] = __builtin_amdgcn_mfma_f32_16x16x32_bf16(a1, b3, acc[1][3], 0, 0, 0);
        acc[2][0] = __builtin_amdgcn_mfma_f32_16x16x32_bf16(a2, b0, acc[2][0], 0, 0, 0);
        acc[2][1] = __builtin_amdgcn_mfma_f32_16x16x32_bf16(a2, b1, acc[2][1], 0, 0, 0);
        acc[2][2] = __builtin_amdgcn_mfma_f32_16x16x32_bf16(a2, b2, acc[2][2], 0, 0, 0);
        acc[2][3] = __builtin_amdgcn_mfma_f32_16x16x32_bf16(a2, b3, acc[2][3], 0, 0, 0);
        acc[3][0] = __builtin_amdgcn_mfma_f32_16x16x32_bf16(a3, b0, acc[3][0], 0, 0, 0);
        acc[3][1] = __builtin_amdgcn_mfma_f32_16x16x32_bf16(a3, b1, acc[3][1], 0, 0, 0);
        acc[3][2] = __builtin_amdgcn_mfma_f32_16x16x32_bf16(a3, b2, acc[3][2], 0, 0, 0);
        acc[3][3] = __builtin_amdgcn_mfma_f32_16x16x32_bf16(a3, b3, acc[3][3], 0, 0, 0);
        acc[4][0] = __builtin_amdgcn_mfma_f32_16x16x32_bf16(a4, b0, acc[4][0], 0, 0, 0);
        acc[4][1] = __builtin_amdgcn_mfma_f32_16x16x32_bf16(a4, b1, acc[4][1], 0, 0, 0);
        acc[4][2] = __builtin_amdgcn_mfma_f32_16x16x32_bf16(a4, b2, acc[4][2], 0, 0, 0);
        acc[4][3] = __builtin_amdgcn_mfma_f32_16x16x32_bf16(a4, b3, acc[4][3], 0, 0, 0);
        acc[5][0] = __builtin_amdgcn_mfma_f32_16x16x32_bf16(a5, b0, acc[5][0], 0, 0, 0);
        acc[5][1] = __builtin_amdgcn_mfma_f32_16x16x32_bf16(a5, b1, acc[5][1], 0, 0, 0);
        acc[5][2] = __builtin_amdgcn_mfma_f32_16x16x32_bf16(a5, b2, acc[5][2], 0, 0, 0);
        acc[5][3] = __builtin_amdgcn_mfma_f32_16x16x32_bf16(a5, b3, acc[5][3], 0, 0, 0);
        acc[6][0] = __builtin_amdgcn_mfma_f32_16x16x32_bf16(a6, b0, acc[6][0], 0, 0, 0);
        acc[6][1] = __builtin_amdgcn_mfma_f32_16x16x32_bf16(a6, b1, acc[6][1], 0, 0, 0);
        acc[6][2] = __builtin_amdgcn_mfma_f32_16x16x32_bf16(a6, b2, acc[6][2], 0, 0, 0);
        acc[6][3] = __builtin_amdgcn_mfma_f32_16x16x32_bf16(a6, b3, acc[6][3], 0, 0, 0);
        acc[7][0] = __builtin_amdgcn_mfma_f32_16x16x32_bf16(a7, b0, acc[7][0], 0, 0, 0);
        acc[7][1] = __builtin_amdgcn_mfma_f32_16x16x32_bf16(a7, b1, acc[7][1], 0, 0, 0);
        acc[7][2] = __builtin_amdgcn_mfma_f32_16x16x32_bf16(a7, b2, acc[7][2], 0, 0, 0);
        acc[7][3] = __builtin_amdgcn_mfma_f32_16x16x32_bf16(a7, b3, acc[7][3], 0, 0, 0);
        __builtin_amdgcn_s_setprio(0);

        // all reads of set ss drained before anyone re-stages into it
        asm volatile("s_waitcnt lgkmcnt(0)" ::: "memory");
        __builtin_amdgcn_s_barrier();
        __builtin_amdgcn_sched_barrier(0);
    }

    // ---- epilogue: C/D col = lane&15, row = (lane>>4)*4 + r (m89-verified)
    const int crow0 = bm * 256 + wr * 128 + (lane >> 4) * 4;
    const int ccol0 = bn * 256 + wc * 64 + (lane & 15);
#pragma unroll
    for (int fm = 0; fm < 8; ++fm)
#pragma unroll
        for (int fn = 0; fn < 4; ++fn)
#pragma unroll
            for (int r = 0; r < 4; ++r)
                C[(size_t)(crow0 + fm * 16 + r) * N + (ccol0 + fn * 16)] = acc[fm][fn][r];

#undef STAGE32
#undef DSA3
#undef DSB3
}

// ---------------- fallback (geometry mismatch only; never taken at 2048x8192x4096) ----------------
__device__ inline int lds_off(int row, int slot) {
    return row * 32 + (((slot ^ ((row >> 1) & 3)) & 3) << 3);
}

__global__ __launch_bounds__(256) void gemm_bt_fused(
    const float* __restrict__ A, const float* __restrict__ B,
    float* __restrict__ C, int M, int N, int K)
{
    constexpr int BM = 128, BN = 128, BK = 32;
    __shared__ unsigned short sA[2][BM * BK];
    __shared__ unsigned short sB[2][BN * BK];

    const int nbm = M / BM, nbn = N / BN;
    const int nwg = nbm * nbn;
    const int bid = blockIdx.x;
    int swz = bid;
    if ((nwg & 7) == 0) { const int q = nwg >> 3; swz = (bid & 7) * q + (bid >> 3); }
    const int bm = swz % nbm, bn = swz / nbm;

    const int tid = threadIdx.x;
    const int srow = tid >> 1;
    const int scol = (tid & 1) * 16;
    const float* gA = A + (size_t)(bm * BM + srow) * K + scol;
    const float* gB = B + (size_t)(bn * BN + srow) * K + scol;
    const int s0  = (tid & 1) * 2;
    const int wo0 = lds_off(srow, s0);
    const int wo1 = lds_off(srow, s0 + 1);

    const int wave = tid >> 6, lane = tid & 63;
    const int wr = wave >> 1, wc = wave & 1;
    const int fr = lane & 15;
    const int slr = lane >> 4;
    int offA[4], offB[4];
#pragma unroll
    for (int i = 0; i < 4; ++i) {
        offA[i] = lds_off(wr * 64 + i * 16 + fr, slr);
        offB[i] = lds_off(wc * 64 + i * 16 + fr, slr);
    }

    f32x4 acc[4][4] = {};
    const int NT = K / BK;

    float4 va[4], vb[4];
#pragma unroll
    for (int p = 0; p < 4; ++p) {
        va[p] = *reinterpret_cast<const float4*>(gA + p * 4);
        vb[p] = *reinterpret_cast<const float4*>(gB + p * 4);
    }

    for (int t = 0; t < NT; ++t) {
        const int cur = t & 1;
        u16x8 pa0, pa1, pb0, pb1;
#pragma unroll
        for (int e = 0; e < 4; ++e) {
            pa0[e] = f2bf(va[0][e]);  pa0[4 + e] = f2bf(va[1][e]);
            pa1[e] = f2bf(va[2][e]);  pa1[4 + e] = f2bf(va[3][e]);
            pb0[e] = f2bf(vb[0][e]);  pb0[4 + e] = f2bf(vb[1][e]);
            pb1[e] = f2bf(vb[2][e]);  pb1[4 + e] = f2bf(vb[3][e]);
        }
        *reinterpret_cast<u16x8*>(&sA[cur][wo0]) = pa0;
        *reinterpret_cast<u16x8*>(&sA[cur][wo1]) = pa1;
        *reinterpret_cast<u16x8*>(&sB[cur][wo0]) = pb0;
        *reinterpret_cast<u16x8*>(&sB[cur][wo1]) = pb1;

        const int kn = (t + 1 < NT) ? (t + 1) * BK : t * BK;
#pragma unroll
        for (int p = 0; p < 4; ++p) {
            va[p] = *reinterpret_cast<const float4*>(gA + kn + p * 4);
            vb[p] = *reinterpret_cast<const float4*>(gB + kn + p * 4);
        }

        __syncthreads();

        bf16x8 a[4], b[4];
#pragma unroll
        for (int i = 0; i < 4; ++i) a[i] = *reinterpret_cast<const bf16x8*>(&sA[cur][offA[i]]);
#pragma unroll
        for (int j = 0; j < 4; ++j) b[j] = *reinterpret_cast<const bf16x8*>(&sB[cur][offB[j]]);
#pragma unroll
        for (int i = 0; i < 4; ++i)
#pragma unroll
            for (int j = 0; j < 4; ++j)
                acc[i][j] = __builtin_amdgcn_mfma_f32_16x16x32_bf16(a[i], b[j], acc[i][j], 0, 0, 0);
    }

    const int crow0 = bm * BM + wr * 64 + (lane >> 4) * 4;
    const int ccol0 = bn * BN + wc * 64 + fr;
#pragma unroll
    for (int i = 0; i < 4; ++i)
#pragma unroll
        for (int j = 0; j < 4; ++j)
#pragma unroll
            for (int r = 0; r < 4; ++r)
                C[(size_t)(crow0 + i * 16 + r) * N + (ccol0 + j * 16)] = acc[i][j][r];
}

extern "C" void kernel_launch(void* const* d_in, const int* in_sizes, int n_in,
                              void* d_out, int out_size, void* d_ws, size_t ws_size,
                              hipStream_t stream) {
    int K = 4096;
    int M = in_sizes[0] / K;   // 2048
    int N = in_sizes[1] / K;   // 8192

    const float* x = (const float*)d_in[0];
    const float* w = (const float*)d_in[1];
    float* out     = (float*)d_out;
    unsigned short* wsp = (unsigned short*)d_ws;

    const size_t szX = (size_t)in_sizes[0], szW = (size_t)in_sizes[1];
    const size_t cntOff = (((szX + szW) * 2) + 255) & ~(size_t)255;
    const size_t need = cntOff + 256;
    unsigned int* cnt = (unsigned int*)((char*)d_ws + cntOff);

    const int nwg2 = (M >> 8) * (N >> 8);   // 256 = 1 block/CU on MI355X

    // Pure-arithmetic path selection: NO runtime API calls (R14 lesson).
    const bool pers_ok = (M % 256 == 0) && (N % 256 == 0) && (K % 64 == 0) &&
                         ((nwg2 & 7) == 0) && (nwg2 <= 256) && (ws_size >= need);

    if (pers_ok) {
        reset_cnt<<<dim3(1), dim3(1), 0, stream>>>(cnt);
        persist_cvt_gemm<<<dim3(nwg2), dim3(512), 0, stream>>>(x, w, wsp, cnt, out, M, N, K);
        return;
    }
    const int nwg = (M / 128) * (N / 128);
    gemm_bt_fused<<<dim3(nwg), dim3(256), 0, stream>>>(x, w, out, M, N, K);
}

// Round 21
// 206.536 us; speedup vs baseline: 1.0590x; 1.0590x over previous
//
#include <hip/hip_runtime.h>
#include <hip/hip_bf16.h>
#include <cstdint>

// out[M,N] = x[M,K] @ weight[N,K]^T, fp32 device buffers.
// TWO plain dispatches, pure-arithmetic path selection (R14 lesson).
//   1) reset_cnt<<<1,1>>>
//   2) persist_cvt_gemm<<<256,512>>> (1 block/CU):
//      phase 1: PIPELINED coalesced LDS-staged cvt fp32->bf16 into d_ws
//               (double-buffered 32KB staging, reg-prefetch next chunk,
//                1 barrier/chunk -> HBM latency hidden under cvt+copyout)
//      agent-scope atomic grid barrier
//      phase 2: 256x256 GEMM, BK=64, 8 waves, 16x16x32 MFMA publish-once
//               vmcnt(2) K-step — R14 EXACT (best timed, 205.6 us).
// R21 = R20 with compile fix: no array-of-LDS-pointers (gfx950 rejects the
// static addrspacecast initializer); buffer selected by ternary per iter.

typedef __bf16 bf16x8 __attribute__((ext_vector_type(8)));
typedef float f32x4 __attribute__((ext_vector_type(4)));
typedef unsigned short u16x8 __attribute__((ext_vector_type(8)));

#define GAS __attribute__((address_space(1)))
#define LAS __attribute__((address_space(3)))
#define ASYNC16(gsrc, ldst)                                                  \
    __builtin_amdgcn_global_load_lds((GAS uint32_t*)(const void*)(gsrc),     \
                                     (LAS uint32_t*)(ldst), 16, 0, 0)

__device__ inline unsigned short f2bf(float f) {
    __hip_bfloat16 h = __float2bfloat16(f);  // RNE
    return *reinterpret_cast<unsigned short*>(&h);
}

__global__ void reset_cnt(unsigned int* cnt) {
    atomicExch(cnt, 0u);
}

__global__ __launch_bounds__(512, 1) void persist_cvt_gemm(
    const float* __restrict__ A32,       // x      [M,K]
    const float* __restrict__ B32,       // weight [N,K]
    unsigned short* __restrict__ ws,     // bf16 tiled [szX | szW]
    unsigned int* __restrict__ cnt,      // grid-barrier counter
    float* __restrict__ C,               // out    [M,N]
    int M, int N, int K)
{
    const int NT  = K >> 6;              // 64 K-steps (chunks of 16384 shorts)
    const int szX = M * K;
    const int szW = N * K;

    __shared__ unsigned short lds[2][2][16384];  // 128 KB (GEMM dbuf; 2x32KB reused by cvt)

    const int tid = threadIdx.x;

    // ================= phase 1: PIPELINED coalesced LDS-staged cvt ============
    // chunk = one (tile256, kt64): [koct 8][row 256][8] bf16 = 32 KB in ws;
    // off = koct*2048 + row*8, k_local = koct*8.  Two alternating staging
    // buffers (selected by ternary, NOT a pointer array - gfx950 compile);
    // next chunk's global loads issued before the barrier so HBM latency
    // hides under cvt + copy-out. One barrier/chunk (hazard audit: write
    // cbuf[x]@i+2 is after barrier i+1; copyout cbuf[x]@i precedes barrier
    // i+1 with its ds_reads drained by __syncthreads).
    {
        const int CH_A = (M >> 8) * NT;
        const int CH_T = CH_A + (N >> 8) * NT;       // 2560 = 10 * 256 exactly

        const int row0 = tid >> 3;                   // 0..63
        const int kg   = tid & 7;                    // 8-float group

        float4 v[8];
        int c = blockIdx.x;
        // prologue: load chunk c
        if (c < CH_T) {
            int cl; const float* base;
            if (c < CH_A) { cl = c;        base = A32; }
            else          { cl = c - CH_A; base = B32; }
            const float* srcc = base + ((size_t)((cl >> 6) << 8)) * K + ((cl & 63) << 6);
#pragma unroll
            for (int p = 0; p < 4; ++p) {
                const float* s = srcc + (size_t)((p << 6) + row0) * K + (kg << 3);
                v[2 * p]     = *reinterpret_cast<const float4*>(s);
                v[2 * p + 1] = *reinterpret_cast<const float4*>(s + 4);
            }
        }
        int cur = 0;
        for (; c < CH_T; c += gridDim.x) {
            unsigned short* cbuf = cur ? &lds[0][1][0] : &lds[0][0][0];
            // convert + LDS write (current chunk)
#pragma unroll
            for (int p = 0; p < 4; ++p) {
                u16x8 o;
                o[0] = f2bf(v[2*p].x);   o[1] = f2bf(v[2*p].y);
                o[2] = f2bf(v[2*p].z);   o[3] = f2bf(v[2*p].w);
                o[4] = f2bf(v[2*p+1].x); o[5] = f2bf(v[2*p+1].y);
                o[6] = f2bf(v[2*p+1].z); o[7] = f2bf(v[2*p+1].w);
                *reinterpret_cast<u16x8*>(&cbuf[kg * 2048 + ((p << 6) + row0) * 8]) = o;
            }
            // prefetch next chunk into registers (overlaps barrier + copyout)
            const int cn = c + gridDim.x;
            if (cn < CH_T) {
                int cl; const float* base;
                if (cn < CH_A) { cl = cn;        base = A32; }
                else           { cl = cn - CH_A; base = B32; }
                const float* srcc = base + ((size_t)((cl >> 6) << 8)) * K + ((cl & 63) << 6);
#pragma unroll
                for (int p = 0; p < 4; ++p) {
                    const float* s = srcc + (size_t)((p << 6) + row0) * K + (kg << 3);
                    v[2 * p]     = *reinterpret_cast<const float4*>(s);
                    v[2 * p + 1] = *reinterpret_cast<const float4*>(s + 4);
                }
            }
            __syncthreads();
            // coalesced linear copy LDS -> ws (16B/lane)
            unsigned short* dstc = (c < CH_A)
                ? ws + ((size_t)c << 14)
                : ws + (size_t)szX + ((size_t)(c - CH_A) << 14);
#pragma unroll
            for (int p = 0; p < 4; ++p) {
                const int off = (p << 12) + (tid << 3);
                *reinterpret_cast<u16x8*>(dstc + off) =
                    *reinterpret_cast<const u16x8*>(&cbuf[off]);
            }
            cur ^= 1;
        }
    }

    // ============ grid barrier (agent scope) ============
    {
        __syncthreads();
        if (tid == 0) {
            __threadfence();
            __hip_atomic_fetch_add(cnt, 1u, __ATOMIC_ACQ_REL, __HIP_MEMORY_SCOPE_AGENT);
            while (__hip_atomic_load(cnt, __ATOMIC_ACQUIRE, __HIP_MEMORY_SCOPE_AGENT)
                   < gridDim.x) {
                __builtin_amdgcn_s_sleep(2);
            }
        }
        __syncthreads();
    }
    asm volatile("s_waitcnt vmcnt(0)" ::: "memory");   // clean vmcnt ledger

    // ================= phase 2: GEMM (R14 EXACT = 16x16x32 publish-once) ======
    const int nbm = M >> 8;              // 8
    const int nbn = N >> 8;              // 32
    const int bid = blockIdx.x;
    const int swzid = (bid & 7) * ((nbm * nbn) >> 3) + (bid >> 3);
    const int bm = swzid % nbm;          // fast: stream A panels
    const int bn = swzid / nbm;          // slow: B panel L2-resident

    const int wv   = tid >> 6;
    const int lane = tid & 63;
    const int wr   = wv >> 2;            // 0..1
    const int wc   = wv & 3;             // 0..3

    const unsigned short* wsA = ws + (size_t)(bm * NT) * 16384 + wv * 1024 + lane * 8;
    const unsigned short* wsB = ws + (size_t)szX + (size_t)(bn * NT) * 16384 + wv * 1024 + lane * 8;
    const int ldsWOff = wv * 1024;

    const int aBase = (lane >> 4) * 2048 + (wr * 128 + (lane & 15)) * 8;
    const int bBase = (lane >> 4) * 2048 + (wc * 64 + (lane & 15)) * 8;

    f32x4 acc[8][4] = {};

#define STAGE_A(half, tt, ss) do {                                            \
        const unsigned short* s_ = wsA + (size_t)(tt) * 16384 + (half) * 8192;\
        ASYNC16(s_,       &lds[ss][0][(half) * 8192 + ldsWOff]);              \
        ASYNC16(s_ + 512, &lds[ss][0][(half) * 8192 + ldsWOff + 512]);        \
    } while (0)
#define STAGE_B(half, tt, ss) do {                                            \
        const unsigned short* s_ = wsB + (size_t)(tt) * 16384 + (half) * 8192;\
        ASYNC16(s_,       &lds[ss][1][(half) * 8192 + ldsWOff]);              \
        ASYNC16(s_ + 512, &lds[ss][1][(half) * 8192 + ldsWOff + 512]);        \
    } while (0)
#define DSA(ss, ks, fm) (*(const bf16x8*)&lds[ss][0][(ks) * 8192 + aBase + (fm) * 128])
#define DSB(ss, ks, fn) (*(const bf16x8*)&lds[ss][1][(ks) * 8192 + bBase + (fn) * 128])
#define CLUSTER(mh, A0_, A1_, A2_, A3_, B0_, B1_, B2_, B3_) do {              \
        __builtin_amdgcn_s_setprio(1);                                        \
        acc[(mh)*4+0][0] = __builtin_amdgcn_mfma_f32_16x16x32_bf16(A0_, B0_, acc[(mh)*4+0][0], 0, 0, 0); \
        acc[(mh)*4+0][1] = __builtin_amdgcn_mfma_f32_16x16x32_bf16(A0_, B1_, acc[(mh)*4+0][1], 0, 0, 0); \
        acc[(mh)*4+0][2] = __builtin_amdgcn_mfma_f32_16x16x32_bf16(A0_, B2_, acc[(mh)*4+0][2], 0, 0, 0); \
        acc[(mh)*4+0][3] = __builtin_amdgcn_mfma_f32_16x16x32_bf16(A0_, B3_, acc[(mh)*4+0][3], 0, 0, 0); \
        acc[(mh)*4+1][0] = __builtin_amdgcn_mfma_f32_16x16x32_bf16(A1_, B0_, acc[(mh)*4+1][0], 0, 0, 0); \
        acc[(mh)*4+1][1] = __builtin_amdgcn_mfma_f32_16x16x32_bf16(A1_, B1_, acc[(mh)*4+1][1], 0, 0, 0); \
        acc[(mh)*4+1][2] = __builtin_amdgcn_mfma_f32_16x16x32_bf16(A1_, B2_, acc[(mh)*4+1][2], 0, 0, 0); \
        acc[(mh)*4+1][3] = __builtin_amdgcn_mfma_f32_16x16x32_bf16(A1_, B3_, acc[(mh)*4+1][3], 0, 0, 0); \
        acc[(mh)*4+2][0] = __builtin_amdgcn_mfma_f32_16x16x32_bf16(A2_, B0_, acc[(mh)*4+2][0], 0, 0, 0); \
        acc[(mh)*4+2][1] = __builtin_amdgcn_mfma_f32_16x16x32_bf16(A2_, B1_, acc[(mh)*4+2][1], 0, 0, 0); \
        acc[(mh)*4+2][2] = __builtin_amdgcn_mfma_f32_16x16x32_bf16(A2_, B2_, acc[(mh)*4+2][2], 0, 0, 0); \
        acc[(mh)*4+2][3] = __builtin_amdgcn_mfma_f32_16x16x32_bf16(A2_, B3_, acc[(mh)*4+2][3], 0, 0, 0); \
        acc[(mh)*4+3][0] = __builtin_amdgcn_mfma_f32_16x16x32_bf16(A3_, B0_, acc[(mh)*4+3][0], 0, 0, 0); \
        acc[(mh)*4+3][1] = __builtin_amdgcn_mfma_f32_16x16x32_bf16(A3_, B1_, acc[(mh)*4+3][1], 0, 0, 0); \
        acc[(mh)*4+3][2] = __builtin_amdgcn_mfma_f32_16x16x32_bf16(A3_, B2_, acc[(mh)*4+3][2], 0, 0, 0); \
        acc[(mh)*4+3][3] = __builtin_amdgcn_mfma_f32_16x16x32_bf16(A3_, B3_, acc[(mh)*4+3][3], 0, 0, 0); \
        __builtin_amdgcn_s_setprio(0);                                        \
    } while (0)
// One K-step: compute set ss, stage tile tn -> ss^1. vmcnt ledger/wave:
// start 8 outstanding (set ss); +2 (A0') -> 10; vmcnt(2) retires all 8 of
// ss -> publish barrier. Clusters then run barrier-free (ds_reads of
// cluster p+1 overlap cluster p's MFMA). End barrier protects set ss.
#define KSTEP(ss, tn) do {                                                    \
        STAGE_A(0, tn, (ss)^1);                                               \
        asm volatile("s_waitcnt vmcnt(2)" ::: "memory");                      \
        __builtin_amdgcn_s_barrier();                                         \
        __builtin_amdgcn_sched_barrier(0);                                    \
        bf16x8 a0 = DSA(ss,0,0), a1 = DSA(ss,0,1), a2 = DSA(ss,0,2), a3 = DSA(ss,0,3); \
        bf16x8 b0 = DSB(ss,0,0), b1 = DSB(ss,0,1), b2 = DSB(ss,0,2), b3 = DSB(ss,0,3); \
        STAGE_B(0, tn, (ss)^1);                                               \
        CLUSTER(0, a0, a1, a2, a3, b0, b1, b2, b3);                           \
        bf16x8 a4 = DSA(ss,0,4), a5 = DSA(ss,0,5), a6 = DSA(ss,0,6), a7 = DSA(ss,0,7); \
        STAGE_A(1, tn, (ss)^1);                                               \
        CLUSTER(1, a4, a5, a6, a7, b0, b1, b2, b3);                           \
        bf16x8 c0 = DSA(ss,1,0), c1 = DSA(ss,1,1), c2 = DSA(ss,1,2), c3 = DSA(ss,1,3); \
        bf16x8 d0 = DSB(ss,1,0), d1 = DSB(ss,1,1), d2 = DSB(ss,1,2), d3 = DSB(ss,1,3); \
        STAGE_B(1, tn, (ss)^1);                                               \
        CLUSTER(0, c0, c1, c2, c3, d0, d1, d2, d3);                           \
        bf16x8 c4 = DSA(ss,1,4), c5 = DSA(ss,1,5), c6 = DSA(ss,1,6), c7 = DSA(ss,1,7); \
        CLUSTER(1, c4, c5, c6, c7, d0, d1, d2, d3);                           \
        __builtin_amdgcn_s_barrier();                                         \
        __builtin_amdgcn_sched_barrier(0);                                    \
    } while (0)

    // prologue: tile 0 -> set 0 (outstanding = 8, matches steady state)
    STAGE_A(0, 0, 0);
    STAGE_B(0, 0, 0);
    STAGE_A(1, 0, 0);
    STAGE_B(1, 0, 0);

    for (int t = 0; t < NT; t += 2) {
        const int tn1 = t + 1;
        KSTEP(0, tn1);
        const int tn2 = (t + 2 < NT) ? t + 2 : NT - 1;
        KSTEP(1, tn2);
    }

    // ---- epilogue: C/D col = lane&15, row = (lane>>4)*4 + r (m89-verified)
    const int crow0 = bm * 256 + wr * 128 + (lane >> 4) * 4;
    const int ccol0 = bn * 256 + wc * 64 + (lane & 15);
#pragma unroll
    for (int fm = 0; fm < 8; ++fm)
#pragma unroll
        for (int fn = 0; fn < 4; ++fn)
#pragma unroll
            for (int r = 0; r < 4; ++r)
                C[(size_t)(crow0 + fm * 16 + r) * N + (ccol0 + fn * 16)] = acc[fm][fn][r];

#undef STAGE_A
#undef STAGE_B
#undef DSA
#undef DSB
#undef CLUSTER
#undef KSTEP
}

// ---------------- fallback (geometry mismatch only; never taken at 2048x8192x4096) ----------------
__device__ inline int lds_off(int row, int slot) {
    return row * 32 + (((slot ^ ((row >> 1) & 3)) & 3) << 3);
}

__global__ __launch_bounds__(256) void gemm_bt_fused(
    const float* __restrict__ A, const float* __restrict__ B,
    float* __restrict__ C, int M, int N, int K)
{
    constexpr int BM = 128, BN = 128, BK = 32;
    __shared__ unsigned short sA[2][BM * BK];
    __shared__ unsigned short sB[2][BN * BK];

    const int nbm = M / BM, nbn = N / BN;
    const int nwg = nbm * nbn;
    const int bid = blockIdx.x;
    int swz = bid;
    if ((nwg & 7) == 0) { const int q = nwg >> 3; swz = (bid & 7) * q + (bid >> 3); }
    const int bm = swz % nbm, bn = swz / nbm;

    const int tid = threadIdx.x;
    const int srow = tid >> 1;
    const int scol = (tid & 1) * 16;
    const float* gA = A + (size_t)(bm * BM + srow) * K + scol;
    const float* gB = B + (size_t)(bn * BN + srow) * K + scol;
    const int s0  = (tid & 1) * 2;
    const int wo0 = lds_off(srow, s0);
    const int wo1 = lds_off(srow, s0 + 1);

    const int wave = tid >> 6, lane = tid & 63;
    const int wr = wave >> 1, wc = wave & 1;
    const int fr = lane & 15;
    const int slr = lane >> 4;
    int offA[4], offB[4];
#pragma unroll
    for (int i = 0; i < 4; ++i) {
        offA[i] = lds_off(wr * 64 + i * 16 + fr, slr);
        offB[i] = lds_off(wc * 64 + i * 16 + fr, slr);
    }

    f32x4 acc[4][4] = {};
    const int NT = K / BK;

    float4 va[4], vb[4];
#pragma unroll
    for (int p = 0; p < 4; ++p) {
        va[p] = *reinterpret_cast<const float4*>(gA + p * 4);
        vb[p] = *reinterpret_cast<const float4*>(gB + p * 4);
    }

    for (int t = 0; t < NT; ++t) {
        const int cur = t & 1;
        u16x8 pa0, pa1, pb0, pb1;
#pragma unroll
        for (int e = 0; e < 4; ++e) {
            pa0[e] = f2bf(va[0][e]);  pa0[4 + e] = f2bf(va[1][e]);
            pa1[e] = f2bf(va[2][e]);  pa1[4 + e] = f2bf(va[3][e]);
            pb0[e] = f2bf(vb[0][e]);  pb0[4 + e] = f2bf(vb[1][e]);
            pb1[e] = f2bf(vb[2][e]);  pb1[4 + e] = f2bf(vb[3][e]);
        }
        *reinterpret_cast<u16x8*>(&sA[cur][wo0]) = pa0;
        *reinterpret_cast<u16x8*>(&sA[cur][wo1]) = pa1;
        *reinterpret_cast<u16x8*>(&sB[cur][wo0]) = pb0;
        *reinterpret_cast<u16x8*>(&sB[cur][wo1]) = pb1;

        const int kn = (t + 1 < NT) ? (t + 1) * BK : t * BK;
#pragma unroll
        for (int p = 0; p < 4; ++p) {
            va[p] = *reinterpret_cast<const float4*>(gA + kn + p * 4);
            vb[p] = *reinterpret_cast<const float4*>(gB + kn + p * 4);
        }

        __syncthreads();

        bf16x8 a[4], b[4];
#pragma unroll
        for (int i = 0; i < 4; ++i) a[i] = *reinterpret_cast<const bf16x8*>(&sA[cur][offA[i]]);
#pragma unroll
        for (int j = 0; j < 4; ++j) b[j] = *reinterpret_cast<const bf16x8*>(&sB[cur][offB[j]]);
#pragma unroll
        for (int i = 0; i < 4; ++i)
#pragma unroll
            for (int j = 0; j < 4; ++j)
                acc[i][j] = __builtin_amdgcn_mfma_f32_16x16x32_bf16(a[i], b[j], acc[i][j], 0, 0, 0);
    }

    const int crow0 = bm * BM + wr * 64 + (lane >> 4) * 4;
    const int ccol0 = bn * BN + wc * 64 + fr;
#pragma unroll
    for (int i = 0; i < 4; ++i)
#pragma unroll
        for (int j = 0; j < 4; ++j)
#pragma unroll
            for (int r = 0; r < 4; ++r)
                C[(size_t)(crow0 + i * 16 + r) * N + (ccol0 + j * 16)] = acc[i][j][r];
}

extern "C" void kernel_launch(void* const* d_in, const int* in_sizes, int n_in,
                              void* d_out, int out_size, void* d_ws, size_t ws_size,
                              hipStream_t stream) {
    int K = 4096;
    int M = in_sizes[0] / K;   // 2048
    int N = in_sizes[1] / K;   // 8192

    const float* x = (const float*)d_in[0];
    const float* w = (const float*)d_in[1];
    float* out     = (float*)d_out;
    unsigned short* wsp = (unsigned short*)d_ws;

    const size_t szX = (size_t)in_sizes[0], szW = (size_t)in_sizes[1];
    const size_t cntOff = (((szX + szW) * 2) + 255) & ~(size_t)255;
    const size_t need = cntOff + 256;
    unsigned int* cnt = (unsigned int*)((char*)d_ws + cntOff);

    const int nwg2 = (M >> 8) * (N >> 8);   // 256 = 1 block/CU on MI355X

    // Pure-arithmetic path selection: NO runtime API calls (R14 lesson).
    const bool pers_ok = (M % 256 == 0) && (N % 256 == 0) && (K % 64 == 0) &&
                         ((nwg2 & 7) == 0) && (nwg2 <= 256) && (ws_size >= need);

    if (pers_ok) {
        reset_cnt<<<dim3(1), dim3(1), 0, stream>>>(cnt);
        persist_cvt_gemm<<<dim3(nwg2), dim3(512), 0, stream>>>(x, w, wsp, cnt, out, M, N, K);
        return;
    }
    const int nwg = (M / 128) * (N / 128);
    gemm_bt_fused<<<dim3(nwg), dim3(256), 0, stream>>>(x, w, out, M, N, K);
}